// Round 3
// baseline (232.924 us; speedup 1.0000x reference)
//
#include <hip/hip_runtime.h>

#define N 4096
#define CORE_W 116        // core columns per strip
#define NSTRIP 36         // 36*116 = 4176 >= 4096
#define ROWS 29           // output rows per wave; ingest steps = ROWS+10 = 39
#define NCHUNK 142        // 142*29 = 4118 >= 4096
#define ITERS 5
#define NSLOT 32          // atomic spreading slots (32 copies of 2 counters)
#define WPB 4             // waves per block (independent waves, no LDS/barriers)
#define NBLOCK ((NSTRIP * NCHUNK) / WPB)   // 5112/4 = 1278

// One wave (64 lanes) owns a 128-wide column strip (2 cols/lane, global
// cols [x0, x0+128), x0 = strip*116 - 6, core cols [x0+6, x0+122)). It
// marches down rows keeping the 5-stage recurrence in rolling REGISTERS:
// at ingest row t it computes iter1 row t-1 ... iter5 row t-5. Horizontal
// stencil via __shfl lane+-1 (1 col/stage edge contamination; core margin 6).
// Warm-up: correctness cascade gives correct_j(r) for r >= t0+j, so t0 =
// R0-5 makes iter5 exact from row R0; zero-init state is finite garbage
// that only reaches iter5 rows < R0 (discarded by row guards). gt prologue
// rows provably uninfluential -> zeros. No LDS, no barriers.
//
// Occupancy model (R0-R2 evidence): gfx950 arch-VGPR occupancy budget is
// 256 regs/wave-slot per SIMD (launch_bounds(256,8) clamped to 32=256/8;
// VGPR=60 measured 37% occ = 4 waves/SIMD = floor(256/64)). Ladder:
// <=32->8, <=40->6, <=48->5, <=64->4 waves/SIMD.
// R3: register diet to cross the 48 boundary (5 waves/SIMD):
//  - h-rings (3-slot, 30 regs) -> running pair sums hp/ps (20 regs):
//    d = hn + ps; ps = hn + hp; hp = hn   (same VALU count, -10 regs)
//  - distance weights fused into ONE accumulator sw (-4 regs, 2 atomics)
//  - __launch_bounds__(256,5): allocator cap 51 -> target <=48, no spill
//    (tripwire: WRITE_SIZE must stay ~1.5MB; R1's forced -24 squeeze
//    spilled 842MB)
//  - ROWS=29: 5112 waves = 1278 blocks = exactly one residency round at
//    5 waves/SIMD (254 CUs x 5 blocks); warm-up overhead 36% -> 26%.

typedef float2 f2;
__device__ __forceinline__ f2 mkf2(float a, float b){ f2 r; r.x=a; r.y=b; return r; }

__device__ __forceinline__ f2 hsum(f2 v) {
    float m = v.x + v.y;
    float L = __shfl_up(v.y, 1);     // lane l-1's right col (intra-wave, width 64)
    float R = __shfl_down(v.x, 1);   // lane l+1's left col
    return mkf2(L + m, m + R);
}

__device__ __forceinline__ f2 stepf(f2 p, f2 d, f2 g, f2* fn) {
    const float C1 = 28.853900817779268f;   // 20*log2(e)
    const float C2 = 14.426950408889634f;   // 10*log2(e)
    f2 o, f;
    {
        float dd = fminf(fmaxf(d.x, 0.f), 1.f);
        float u  = __builtin_fmaf(p.x - dd, C1, C2);
        float sh = __builtin_amdgcn_rcpf(1.f + __builtin_amdgcn_exp2f(u));
        f.x = g.x * sh; o.x = p.x + f.x;
    }
    {
        float dd = fminf(fmaxf(d.y, 0.f), 1.f);
        float u  = __builtin_fmaf(p.y - dd, C1, C2);
        float sh = __builtin_amdgcn_rcpf(1.f + __builtin_amdgcn_exp2f(u));
        f.y = g.y * sh; o.y = p.y + f.y;
    }
    *fn = f;
    return o;
}

__device__ __forceinline__ f2 ldrow(const float* __restrict__ base, int row,
                                    int gc, bool edge) {
    if (row < 0 || row >= N) return mkf2(0.f, 0.f);
    if (!edge) return *(const f2*)(base + (size_t)row * N + gc);  // gc even -> aligned
    float a = 0.f, b = 0.f;
    if (gc >= 0 && gc < N)         a = base[(size_t)row * N + gc];
    if (gc + 1 >= 0 && gc + 1 < N) b = base[(size_t)row * N + gc + 1];
    return mkf2(a, b);
}

__global__ __launch_bounds__(64 * WPB, 5) void wlc_main(
    const float* __restrict__ pred,
    const float* __restrict__ gt,
    float* __restrict__ ws)
{
    const int lane   = threadIdx.x & 63;
    const int wid    = threadIdx.x >> 6;
    const int linear = blockIdx.x * WPB + wid;      // adjacent strips share a block
    const int strip  = linear % NSTRIP;
    const int chunk  = linear / NSTRIP;
    const int x0 = strip * CORE_W - 6;
    const int gc = x0 + 2 * lane;
    const bool edge = (strip == 0) || (strip == NSTRIP - 1);

    const int R0 = chunk * ROWS;
    const int R1 = min(R0 + ROWS, N);
    const int t0 = R0 - 5;           // 5-row warm-up (cascade-minimal)
    const int t1 = R1 + 5;           // 5-row drain (pipeline depth)

    // column accumulation masks: core cols -> lanes 3..60
    const float colm = (lane >= 3 && lane <= 60) ? 1.f : 0.f;
    const float m0 = (gc     < N) ? colm : 0.f;
    const float m1 = (gc + 1 < N) ? colm : 0.f;

    // rolling state (all registers; zero-init -> finite warm-up garbage)
    f2 pr[6], gb[6];
    f2 hp0, hp1, hp2, hp3, hp4;       // newest hsum per stage
    f2 ps0, ps1, ps2, ps3, ps4;       // sum of previous two hsums per stage
    f2 o1[2], o2[2], o3[2], o4[2];
#pragma unroll
    for (int i = 0; i < 6; ++i) { pr[i] = mkf2(0,0); gb[i] = mkf2(0,0); }
    hp0=hp1=hp2=hp3=hp4=mkf2(0,0);
    ps0=ps1=ps2=ps3=ps4=mkf2(0,0);
#pragma unroll
    for (int i = 0; i < 2; ++i) { o1[i]=o2[i]=o3[i]=o4[i]=mkf2(0,0); }

    // prologue: slots are relative to (t - t0): row t0 -> slot 2, t0+1 -> 3.
    // gt prologue rows (< R0-4) are provably uninfluential -> stay zero;
    // real gt rows R0-4..R1+3 arrive via the t+1 prefetch.
    pr[2] = ldrow(pred, t0,     gc, edge);
    pr[3] = ldrow(pred, t0 + 1, gc, edge);

    float sw = 0.f, gsa = 0.f;        // weighted fn total, gt total

    // compile-time slot macros for row t+o (valid o >= -5)
#define S6(o) ((8 + k + (o)) % 6)
#define S2(o) ((8 + k + (o)) % 2)

    for (int tb = t0; tb < t1; tb += 6) {
#pragma unroll
        for (int k = 0; k < 6; ++k) {
            const int t = tb + k;
            if (t < t1) {
                // save gt row t-5 before its slot is reloaded with row t+1
                const f2 g5 = gb[S6(-5)];
                // prefetch (2-row slack); trim useless drain loads
                if (t + 2 <= R1 + 4) pr[S6(2)] = ldrow(pred, t + 2, gc, edge);
                if (t + 1 <= R1 + 3) gb[S6(1)] = ldrow(gt,   t + 1, gc, edge);

                f2 hn, d, fn, o;

                // feed: h-sum of input row t
                hn = hsum(pr[S6(0)]);
                d  = mkf2(hn.x + ps0.x, hn.y + ps0.y);      // rows t,t-1,t-2
                ps0 = mkf2(hn.x + hp0.x, hn.y + hp0.y);
                hp0 = hn;

                // stage 1: row t-1
                o = stepf(pr[S6(-1)], d, gb[S6(-1)], &fn);
                { int r = t - 1; if (r >= R0 && r < R1)
                    sw += 1.f * (fn.x*m0 + fn.y*m1); }
                hn = hsum(o);  o1[S2(-1)] = o;
                d  = mkf2(hn.x + ps1.x, hn.y + ps1.y);
                ps1 = mkf2(hn.x + hp1.x, hn.y + hp1.y);
                hp1 = hn;

                // stage 2: row t-2
                o = stepf(o1[S2(-2)], d, gb[S6(-2)], &fn);
                { int r = t - 2; if (r >= R0 && r < R1)
                    sw += 4.f * (fn.x*m0 + fn.y*m1); }
                hn = hsum(o);  o2[S2(-2)] = o;
                d  = mkf2(hn.x + ps2.x, hn.y + ps2.y);
                ps2 = mkf2(hn.x + hp2.x, hn.y + hp2.y);
                hp2 = hn;

                // stage 3: row t-3
                o = stepf(o2[S2(-3)], d, gb[S6(-3)], &fn);
                { int r = t - 3; if (r >= R0 && r < R1)
                    sw += 9.f * (fn.x*m0 + fn.y*m1); }
                hn = hsum(o);  o3[S2(-3)] = o;
                d  = mkf2(hn.x + ps3.x, hn.y + ps3.y);
                ps3 = mkf2(hn.x + hp3.x, hn.y + hp3.y);
                hp3 = hn;

                // stage 4: row t-4
                o = stepf(o3[S2(-4)], d, gb[S6(-4)], &fn);
                { int r = t - 4; if (r >= R0 && r < R1)
                    sw += 16.f * (fn.x*m0 + fn.y*m1); }
                hn = hsum(o);  o4[S2(-4)] = o;
                d  = mkf2(hn.x + ps4.x, hn.y + ps4.y);
                ps4 = mkf2(hn.x + hp4.x, hn.y + hp4.y);
                hp4 = hn;

                // stage 5: row t-5 (output not fed forward)
                o = stepf(o4[S2(-5)], d, g5, &fn);
                { int r = t - 5;
                  if (r >= R0 && r < R1) {
                      sw  += 25.f * (fn.x*m0 + fn.y*m1);
                      gsa += g5.x*m0 + g5.y*m1;
                  } }
            }
        }
    }
#undef S6
#undef S2

    // wave reduction -> 2 atomics, spread over NSLOT slot copies
    float vals[2] = {gsa, sw};
    const int slot = (strip + chunk * NSTRIP) & (NSLOT - 1);
#pragma unroll
    for (int kk = 0; kk < 2; ++kk) {
        float v = vals[kk];
#pragma unroll
        for (int off = 32; off > 0; off >>= 1)
            v += __shfl_down(v, off, 64);
        if (lane == 0) atomicAdd(&ws[slot * 32 + kk], v);
    }
}

__global__ __launch_bounds__(64) void wlc_final(const float* __restrict__ ws,
                                                float* __restrict__ out)
{
    const int lane = threadIdx.x;
    float t0 = (lane < NSLOT) ? ws[lane * 32 + 0] : 0.f;
    float t1 = (lane < NSLOT) ? ws[lane * 32 + 1] : 0.f;
#pragma unroll
    for (int off = 32; off > 0; off >>= 1) {
        t0 += __shfl_down(t0, off, 64);
        t1 += __shfl_down(t1, off, 64);
    }
    if (lane == 0)
        out[0] = t1 / t0;
}

extern "C" void kernel_launch(void* const* d_in, const int* in_sizes, int n_in,
                              void* d_out, int out_size, void* d_ws, size_t ws_size,
                              hipStream_t stream)
{
    const float* pred = (const float*)d_in[0];
    const float* gtp  = (const float*)d_in[1];
    float* ws = (float*)d_ws;

    hipMemsetAsync(d_ws, 0, NSLOT * 32 * sizeof(float), stream);

    wlc_main<<<dim3(NBLOCK), 64 * WPB, 0, stream>>>(pred, gtp, ws);
    wlc_final<<<1, 64, 0, stream>>>(ws, (float*)d_out);
}

// Round 4
// 189.696 us; speedup vs baseline: 1.2279x; 1.2279x over previous
//
#include <hip/hip_runtime.h>

#define N 4096
#define CORE_W 116        // core columns per strip
#define NSTRIP 36         // 36*116 = 4176 >= 4096
#define ROWS 36           // output rows per wave; ingest steps = ROWS+10 = 46
#define NCHUNK 114        // 114*36 = 4104 >= 4096
#define NSLOT 32          // atomic spreading slots (32 copies of 2 counters)
#define WPB 4             // waves per block (independent waves, no LDS/barriers)
#define NBLOCK ((NSTRIP * NCHUNK) / WPB)   // 4104/4 = 1026

// One wave (64 lanes) owns a 128-wide column strip (2 cols/lane, global
// cols [x0, x0+128), x0 = strip*116 - 6, core cols [x0+6, x0+122)). It
// marches down rows keeping the 5-stage recurrence in rolling REGISTERS:
// at ingest row t it computes iter1 row t-1 ... iter5 row t-5. Horizontal
// stencil via __shfl lane+-1 (1 col/stage edge contamination; core margin 6).
// Warm-up: correctness cascade gives correct_j(r) for r >= t0+j, so t0 =
// R0-5 makes iter5 exact from row R0; zero-init state is finite garbage
// that only reaches iter5 rows < R0 (annihilated by w=0 selects). gt
// prologue rows provably uninfluential -> zeros. No LDS, no barriers.
//
// Occupancy model (R0-R3 evidence): arch-VGPR budget ~256/SIMD-wave-slot;
// VGPR 56-64 -> 4 waves/SIMD (37-46% occ) regardless of WPB. Forcing the
// 48 cap (R3) or 32 cap (R1) spills the rolling state -> net loss. So:
// natural allocation at (256,4), and instead cut WORK and INSTRUCTIONS:
//  - VALUBusy 51% @ 4 waves/SIMD -> VALU-issue floor ~63us; latency
//    hiding alone caps at ~2x. Cut issue count first.
//  - grid = ONE residency round: 4104 waves x 46 steps = -18% wave-steps
//    vs R2 (8208 x 28, 56% warm-up overhead -> 28%).
//  - mask-at-end: m0/m1 are step-invariant -> accumulate raw fn into f2,
//    mask once in epilogue (-10 VALU/step).
//  - guards -> uniform SALU weight-selects folded into fma (branch-free,
//    SALU co-issues with VALU). Warm-up garbage finite -> w=0 kills it.
// Tripwire: WRITE_SIZE must stay ~1.5MB (no spill).

typedef float2 f2;
__device__ __forceinline__ f2 mkf2(float a, float b){ f2 r; r.x=a; r.y=b; return r; }

__device__ __forceinline__ f2 hsum(f2 v) {
    float m = v.x + v.y;
    float L = __shfl_up(v.y, 1);     // lane l-1's right col (intra-wave, width 64)
    float R = __shfl_down(v.x, 1);   // lane l+1's left col
    return mkf2(L + m, m + R);
}

__device__ __forceinline__ f2 stepf(f2 p, f2 d, f2 g, f2* fn) {
    const float C1 = 28.853900817779268f;   // 20*log2(e)
    const float C2 = 14.426950408889634f;   // 10*log2(e)
    f2 o, f;
    {
        float dd = fminf(fmaxf(d.x, 0.f), 1.f);      // v_med3_f32
        float u  = __builtin_fmaf(p.x - dd, C1, C2);
        float sh = __builtin_amdgcn_rcpf(1.f + __builtin_amdgcn_exp2f(u));
        f.x = g.x * sh; o.x = p.x + f.x;
    }
    {
        float dd = fminf(fmaxf(d.y, 0.f), 1.f);
        float u  = __builtin_fmaf(p.y - dd, C1, C2);
        float sh = __builtin_amdgcn_rcpf(1.f + __builtin_amdgcn_exp2f(u));
        f.y = g.y * sh; o.y = p.y + f.y;
    }
    *fn = f;
    return o;
}

__device__ __forceinline__ f2 ldrow(const float* __restrict__ base, int row,
                                    int gc, bool edge) {
    if (row < 0 || row >= N) return mkf2(0.f, 0.f);
    if (!edge) return *(const f2*)(base + (size_t)row * N + gc);  // gc even -> aligned
    float a = 0.f, b = 0.f;
    if (gc >= 0 && gc < N)         a = base[(size_t)row * N + gc];
    if (gc + 1 >= 0 && gc + 1 < N) b = base[(size_t)row * N + gc + 1];
    return mkf2(a, b);
}

__global__ __launch_bounds__(64 * WPB, 4) void wlc_main(
    const float* __restrict__ pred,
    const float* __restrict__ gt,
    float* __restrict__ ws)
{
    const int lane   = threadIdx.x & 63;
    const int wid    = threadIdx.x >> 6;
    const int linear = blockIdx.x * WPB + wid;      // adjacent strips share a block
    const int strip  = linear % NSTRIP;
    const int chunk  = linear / NSTRIP;
    const int x0 = strip * CORE_W - 6;
    const int gc = x0 + 2 * lane;
    const bool edge = (strip == 0) || (strip == NSTRIP - 1);

    const int R0 = chunk * ROWS;
    const int R1 = min(R0 + ROWS, N);
    const int t0 = R0 - 5;           // 5-row warm-up (cascade-minimal)
    const int t1 = R1 + 5;           // 5-row drain (pipeline depth)

    // column accumulation masks: core cols -> lanes 3..60 (applied ONCE at end)
    const float colm = (lane >= 3 && lane <= 60) ? 1.f : 0.f;
    const float m0 = (gc     < N) ? colm : 0.f;
    const float m1 = (gc + 1 < N) ? colm : 0.f;

    // rolling state (all registers; zero-init -> finite warm-up garbage)
    f2 pr[6], gb[6];
    f2 hp0, hp1, hp2, hp3, hp4;       // newest hsum per stage
    f2 ps0, ps1, ps2, ps3, ps4;       // sum of previous two hsums per stage
    f2 o1[2], o2[2], o3[2], o4[2];
#pragma unroll
    for (int i = 0; i < 6; ++i) { pr[i] = mkf2(0,0); gb[i] = mkf2(0,0); }
    hp0=hp1=hp2=hp3=hp4=mkf2(0,0);
    ps0=ps1=ps2=ps3=ps4=mkf2(0,0);
#pragma unroll
    for (int i = 0; i < 2; ++i) { o1[i]=o2[i]=o3[i]=o4[i]=mkf2(0,0); }

    // prologue: slots are relative to (t - t0): row t0 -> slot 2, t0+1 -> 3.
    // gt prologue rows (< R0-4) are provably uninfluential -> stay zero;
    // real gt rows R0-4..R1+3 arrive via the t+1 prefetch.
    pr[2] = ldrow(pred, t0,     gc, edge);
    pr[3] = ldrow(pred, t0 + 1, gc, edge);

    f2 swv = mkf2(0.f, 0.f);          // weighted fn total (unmasked)
    f2 gsv = mkf2(0.f, 0.f);          // gt total (unmasked)

    // compile-time slot macros for row t+o (valid o >= -5)
#define S6(o) ((8 + k + (o)) % 6)
#define S2(o) ((8 + k + (o)) % 2)

    for (int tb = t0; tb < t1; tb += 6) {
#pragma unroll
        for (int k = 0; k < 6; ++k) {
            const int t = tb + k;
            if (t < t1) {
                // save gt row t-5 before its slot is reloaded with row t+1
                const f2 g5 = gb[S6(-5)];
                // prefetch (2-row slack); trim useless drain loads
                if (t + 2 <= R1 + 4) pr[S6(2)] = ldrow(pred, t + 2, gc, edge);
                if (t + 1 <= R1 + 3) gb[S6(1)] = ldrow(gt,   t + 1, gc, edge);

                // uniform guarded weights (SALU selects, branch-free)
                const float w1 = (t-1 >= R0 && t-1 < R1) ? 1.f  : 0.f;
                const float w2 = (t-2 >= R0 && t-2 < R1) ? 4.f  : 0.f;
                const float w3 = (t-3 >= R0 && t-3 < R1) ? 9.f  : 0.f;
                const float w4 = (t-4 >= R0 && t-4 < R1) ? 16.f : 0.f;
                const bool  in5 = (t-5 >= R0 && t-5 < R1);
                const float w5 = in5 ? 25.f : 0.f;
                const float g1 = in5 ? 1.f  : 0.f;

                f2 hn, d, fn, o;

                // feed: h-sum of input row t
                hn = hsum(pr[S6(0)]);
                d  = mkf2(hn.x + ps0.x, hn.y + ps0.y);      // rows t,t-1,t-2
                ps0 = mkf2(hn.x + hp0.x, hn.y + hp0.y);
                hp0 = hn;

                // stage 1: row t-1
                o = stepf(pr[S6(-1)], d, gb[S6(-1)], &fn);
                swv.x = __builtin_fmaf(w1, fn.x, swv.x);
                swv.y = __builtin_fmaf(w1, fn.y, swv.y);
                hn = hsum(o);  o1[S2(-1)] = o;
                d  = mkf2(hn.x + ps1.x, hn.y + ps1.y);
                ps1 = mkf2(hn.x + hp1.x, hn.y + hp1.y);
                hp1 = hn;

                // stage 2: row t-2
                o = stepf(o1[S2(-2)], d, gb[S6(-2)], &fn);
                swv.x = __builtin_fmaf(w2, fn.x, swv.x);
                swv.y = __builtin_fmaf(w2, fn.y, swv.y);
                hn = hsum(o);  o2[S2(-2)] = o;
                d  = mkf2(hn.x + ps2.x, hn.y + ps2.y);
                ps2 = mkf2(hn.x + hp2.x, hn.y + hp2.y);
                hp2 = hn;

                // stage 3: row t-3
                o = stepf(o2[S2(-3)], d, gb[S6(-3)], &fn);
                swv.x = __builtin_fmaf(w3, fn.x, swv.x);
                swv.y = __builtin_fmaf(w3, fn.y, swv.y);
                hn = hsum(o);  o3[S2(-3)] = o;
                d  = mkf2(hn.x + ps3.x, hn.y + ps3.y);
                ps3 = mkf2(hn.x + hp3.x, hn.y + hp3.y);
                hp3 = hn;

                // stage 4: row t-4
                o = stepf(o3[S2(-4)], d, gb[S6(-4)], &fn);
                swv.x = __builtin_fmaf(w4, fn.x, swv.x);
                swv.y = __builtin_fmaf(w4, fn.y, swv.y);
                hn = hsum(o);  o4[S2(-4)] = o;
                d  = mkf2(hn.x + ps4.x, hn.y + ps4.y);
                ps4 = mkf2(hn.x + hp4.x, hn.y + hp4.y);
                hp4 = hn;

                // stage 5: row t-5 (output not fed forward)
                o = stepf(o4[S2(-5)], d, g5, &fn);
                swv.x = __builtin_fmaf(w5, fn.x, swv.x);
                swv.y = __builtin_fmaf(w5, fn.y, swv.y);
                gsv.x = __builtin_fmaf(g1, g5.x, gsv.x);
                gsv.y = __builtin_fmaf(g1, g5.y, gsv.y);
            }
        }
    }
#undef S6
#undef S2

    // apply step-invariant column masks ONCE, wave-reduce, 2 atomics
    float vals[2];
    vals[0] = gsv.x * m0 + gsv.y * m1;
    vals[1] = swv.x * m0 + swv.y * m1;
    const int slot = (strip + chunk * NSTRIP) & (NSLOT - 1);
#pragma unroll
    for (int kk = 0; kk < 2; ++kk) {
        float v = vals[kk];
#pragma unroll
        for (int off = 32; off > 0; off >>= 1)
            v += __shfl_down(v, off, 64);
        if (lane == 0) atomicAdd(&ws[slot * 32 + kk], v);
    }
}

__global__ __launch_bounds__(64) void wlc_final(const float* __restrict__ ws,
                                                float* __restrict__ out)
{
    const int lane = threadIdx.x;
    float t0 = (lane < NSLOT) ? ws[lane * 32 + 0] : 0.f;
    float t1 = (lane < NSLOT) ? ws[lane * 32 + 1] : 0.f;
#pragma unroll
    for (int off = 32; off > 0; off >>= 1) {
        t0 += __shfl_down(t0, off, 64);
        t1 += __shfl_down(t1, off, 64);
    }
    if (lane == 0)
        out[0] = t1 / t0;
}

extern "C" void kernel_launch(void* const* d_in, const int* in_sizes, int n_in,
                              void* d_out, int out_size, void* d_ws, size_t ws_size,
                              hipStream_t stream)
{
    const float* pred = (const float*)d_in[0];
    const float* gtp  = (const float*)d_in[1];
    float* ws = (float*)d_ws;

    hipMemsetAsync(d_ws, 0, NSLOT * 32 * sizeof(float), stream);

    wlc_main<<<dim3(NBLOCK), 64 * WPB, 0, stream>>>(pred, gtp, ws);
    wlc_final<<<1, 64, 0, stream>>>(ws, (float*)d_out);
}